// Round 6
// baseline (12.979 us; speedup 1.0000x reference)
//
#include <hip/hip_runtime.h>

// CaptionEmbedder: out[b,l,:] = select-by-mask gather of a 512-float row.
//   VOCAB=32000, N_ENT=64, N_FACT=512, D=512, B=128, L=128
//   mask==1 -> entities_encoded[b, clamp(ci - VOCAB, ->N_ENT-1)]
//   mask==2 -> facts_encoded[b, clamp(ci - VOCAB - N_ENT, ->N_FACT-1)]
//   else    -> word_embedding[ci >= VOCAB ? pad : ci]
// R4: NT stores (12.0us). R5: ILP=2 (11.7us). R6: ILP=4, grid=2048 blocks
// -> exactly 32 waves/CU single-pass, 4 in-flight gathers per thread.

constexpr int VOCAB  = 32000;
constexpr int N_ENT  = 64;
constexpr int N_FACT = 512;
constexpr int D      = 512;
constexpr int L      = 128;

typedef float f32x4 __attribute__((ext_vector_type(4)));

constexpr int TPR   = D / 4;   // 128 threads per row, 1 float4 each
constexpr int BLOCK = 256;
constexpr int ILP   = 4;       // rows per thread

__device__ __forceinline__ const f32x4* row_src(
    int ci, int m, int b, int pad,
    const f32x4* __restrict__ ents,
    const f32x4* __restrict__ facts,
    const f32x4* __restrict__ words)
{
    if (m == 1) {
        int e = ci - VOCAB;
        if (e < 0 || e >= N_ENT) e = N_ENT - 1;
        return ents + ((long)b * N_ENT + e) * TPR;
    } else if (m == 2) {
        int f = ci - VOCAB - N_ENT;
        if (f < 0 || f >= N_FACT) f = N_FACT - 1;
        return facts + ((long)b * N_FACT + f) * TPR;
    } else {
        int w = (ci >= VOCAB) ? pad : ci;
        return words + (long)w * TPR;
    }
}

__global__ __launch_bounds__(BLOCK) void caption_embed_kernel(
    const int*   __restrict__ idx,     // [B*L]
    const f32x4* __restrict__ ents,    // [B, N_ENT, D/4]
    const f32x4* __restrict__ facts,   // [B, N_FACT, D/4]
    const f32x4* __restrict__ words,   // [VOCAB, D/4]
    const int*   __restrict__ pad_tok, // [1]
    const int*   __restrict__ masks,   // [B*L]
    f32x4*       __restrict__ out,     // [B*L, D/4]
    int chunk_rows)                    // n_rows / ILP
{
    const int tid  = blockIdx.x * BLOCK + threadIdx.x;
    const int row0 = tid / TPR;        // 0 .. chunk_rows-1
    const int col  = tid % TPR;
    if (row0 >= chunk_rows) return;

    const int pad = pad_tok[0];

    int          rows[ILP];
    const f32x4* srcs[ILP];
#pragma unroll
    for (int k = 0; k < ILP; ++k) {
        const int r = row0 + k * chunk_rows;
        rows[k] = r;
        srcs[k] = row_src(idx[r], masks[r], r / L, pad, ents, facts, words);
    }

    f32x4 v[ILP];
#pragma unroll
    for (int k = 0; k < ILP; ++k) v[k] = srcs[k][col];   // all gathers in flight

#pragma unroll
    for (int k = 0; k < ILP; ++k)
        __builtin_nontemporal_store(v[k], &out[(long)rows[k] * TPR + col]);
}

extern "C" void kernel_launch(void* const* d_in, const int* in_sizes, int n_in,
                              void* d_out, int out_size, void* d_ws, size_t ws_size,
                              hipStream_t stream) {
    const int*   idx     = (const int*)d_in[0];
    const f32x4* ents    = (const f32x4*)d_in[1];
    const f32x4* facts   = (const f32x4*)d_in[2];
    const f32x4* words   = (const f32x4*)d_in[3];
    const int*   pad_tok = (const int*)d_in[4];
    const int*   masks   = (const int*)d_in[5];
    f32x4*       out     = (f32x4*)d_out;

    const int n_rows     = in_sizes[0];          // B*L = 16384
    const int chunk_rows = n_rows / ILP;         // 4096
    const int total      = chunk_rows * TPR;
    const int grid       = (total + BLOCK - 1) / BLOCK;  // 2048

    caption_embed_kernel<<<grid, BLOCK, 0, stream>>>(
        idx, ents, facts, words, pad_tok, masks, out, chunk_rows);
}

// Round 7
// 11.457 us; speedup vs baseline: 1.1329x; 1.1329x over previous
//
#include <hip/hip_runtime.h>

// CaptionEmbedder: out[b,l,:] = select-by-mask gather of a 512-float row.
//   VOCAB=32000, N_ENT=64, N_FACT=512, D=512, B=128, L=128
//   mask==1 -> entities_encoded[b, clamp(ci - VOCAB, ->N_ENT-1)]
//   mask==2 -> facts_encoded[b, clamp(ci - VOCAB - N_ENT, ->N_FACT-1)]
//   else    -> word_embedding[ci >= VOCAB ? pad : ci]
// R5 best (11.67us): ILP=2 + NT stores, BLOCK=256/4096 WGs.
// R7: single variable vs R5 -> BLOCK=1024 (1024 WGs), testing dispatch/ramp cost.

constexpr int VOCAB  = 32000;
constexpr int N_ENT  = 64;
constexpr int N_FACT = 512;
constexpr int D      = 512;
constexpr int L      = 128;

typedef float f32x4 __attribute__((ext_vector_type(4)));

constexpr int TPR   = D / 4;   // 128 threads per row, 1 float4 each
constexpr int BLOCK = 1024;    // 8 rows per block (x2 via ILP)

__device__ __forceinline__ const f32x4* row_src(
    int ci, int m, int b, int pad,
    const f32x4* __restrict__ ents,
    const f32x4* __restrict__ facts,
    const f32x4* __restrict__ words)
{
    if (m == 1) {
        int e = ci - VOCAB;
        if (e < 0 || e >= N_ENT) e = N_ENT - 1;
        return ents + ((long)b * N_ENT + e) * TPR;
    } else if (m == 2) {
        int f = ci - VOCAB - N_ENT;
        if (f < 0 || f >= N_FACT) f = N_FACT - 1;
        return facts + ((long)b * N_FACT + f) * TPR;
    } else {
        int w = (ci >= VOCAB) ? pad : ci;
        return words + (long)w * TPR;
    }
}

__global__ __launch_bounds__(BLOCK) void caption_embed_kernel(
    const int*   __restrict__ idx,     // [B*L]
    const f32x4* __restrict__ ents,    // [B, N_ENT, D/4]
    const f32x4* __restrict__ facts,   // [B, N_FACT, D/4]
    const f32x4* __restrict__ words,   // [VOCAB, D/4]
    const int*   __restrict__ pad_tok, // [1]
    const int*   __restrict__ masks,   // [B*L]
    f32x4*       __restrict__ out,     // [B*L, D/4]
    int half_rows)                     // n_rows / 2
{
    const int tid  = blockIdx.x * BLOCK + threadIdx.x;
    const int row0 = tid / TPR;        // 0 .. half_rows-1
    const int col  = tid % TPR;
    if (row0 >= half_rows) return;
    const int row1 = row0 + half_rows;

    const int pad = pad_tok[0];

    const int ci0 = idx[row0];
    const int m0  = masks[row0];
    const int ci1 = idx[row1];
    const int m1  = masks[row1];

    const f32x4* s0 = row_src(ci0, m0, row0 / L, pad, ents, facts, words);
    const f32x4* s1 = row_src(ci1, m1, row1 / L, pad, ents, facts, words);

    // issue both gathers before consuming either -> 2x MLP
    f32x4 v0 = s0[col];
    f32x4 v1 = s1[col];

    __builtin_nontemporal_store(v0, &out[(long)row0 * TPR + col]);
    __builtin_nontemporal_store(v1, &out[(long)row1 * TPR + col]);
}

extern "C" void kernel_launch(void* const* d_in, const int* in_sizes, int n_in,
                              void* d_out, int out_size, void* d_ws, size_t ws_size,
                              hipStream_t stream) {
    const int*   idx     = (const int*)d_in[0];
    const f32x4* ents    = (const f32x4*)d_in[1];
    const f32x4* facts   = (const f32x4*)d_in[2];
    const f32x4* words   = (const f32x4*)d_in[3];
    const int*   pad_tok = (const int*)d_in[4];
    const int*   masks   = (const int*)d_in[5];
    f32x4*       out     = (f32x4*)d_out;

    const int n_rows    = in_sizes[0];          // B*L = 16384
    const int half_rows = n_rows / 2;
    const int total     = half_rows * TPR;
    const int grid      = (total + BLOCK - 1) / BLOCK;  // 1024

    caption_embed_kernel<<<grid, BLOCK, 0, stream>>>(
        idx, ents, facts, words, pad_tok, masks, out, half_rows);
}